// Round 1
// baseline (434.507 us; speedup 1.0000x reference)
//
#include <hip/hip_runtime.h>
#include <stdint.h>

#define EMBED  768
#define HEADS  12
#define HDIM   64
#define HIDDEN 3072
#define BSZ    2
#define SEQ    2048
#define NTOK   4096
#define QKVN   2304

typedef short short8 __attribute__((ext_vector_type(8)));
typedef float f32x4 __attribute__((ext_vector_type(4)));
typedef float float4v __attribute__((ext_vector_type(4)));
typedef unsigned short ushort4v __attribute__((ext_vector_type(4)));

__device__ __forceinline__ unsigned short f2bf(float f) {
    uint32_t x = __builtin_bit_cast(uint32_t, f);
    x = x + 0x7fffu + ((x >> 16) & 1u);   // RNE
    return (unsigned short)(x >> 16);
}
__device__ __forceinline__ float bf2f(unsigned short u) {
    uint32_t x = ((uint32_t)u) << 16;
    return __builtin_bit_cast(float, x);
}
__device__ __forceinline__ void load16(const void* g, void* l) {
    __builtin_amdgcn_global_load_lds((const __attribute__((address_space(1))) void*)g,
                                     (__attribute__((address_space(3))) void*)l, 16, 0, 0);
}

// ---------------- fp32 -> bf16 convert ----------------
__global__ __launch_bounds__(256) void cvt_k(const float* __restrict__ in,
                                             unsigned short* __restrict__ out, int n4) {
    int i = blockIdx.x * blockDim.x + threadIdx.x;
    int stride = gridDim.x * blockDim.x;
    for (; i < n4; i += stride) {
        float4v v = ((const float4v*)in)[i];
        ushort4v o;
#pragma unroll
        for (int j = 0; j < 4; j++) o[j] = f2bf(v[j]);
        ((ushort4v*)out)[i] = o;
    }
}

// ---------------- LayerNorm (fp32 in, bf16 out) ----------------
__global__ __launch_bounds__(256) void ln_k(const float* __restrict__ x,
                                            const float* __restrict__ g,
                                            const float* __restrict__ b,
                                            unsigned short* __restrict__ out) {
    const int row = blockIdx.x;
    const int t = threadIdx.x;
    const float* xr = x + (size_t)row * EMBED;
    float v0 = xr[t], v1 = xr[t + 256], v2 = xr[t + 512];
    float s = v0 + v1 + v2;
    float s2 = v0 * v0 + v1 * v1 + v2 * v2;
#pragma unroll
    for (int m = 1; m < 64; m <<= 1) { s += __shfl_xor(s, m); s2 += __shfl_xor(s2, m); }
    __shared__ float red[8];
    const int w = t >> 6;
    if ((t & 63) == 0) { red[w] = s; red[4 + w] = s2; }
    __syncthreads();
    s = red[0] + red[1] + red[2] + red[3];
    s2 = red[4] + red[5] + red[6] + red[7];
    const float mu = s * (1.0f / EMBED);
    const float var = s2 * (1.0f / EMBED) - mu * mu;
    const float rs = rsqrtf(var + 1e-5f);
    unsigned short* orow = out + (size_t)row * EMBED;
    orow[t]       = f2bf((v0 - mu) * rs * g[t]       + b[t]);
    orow[t + 256] = f2bf((v1 - mu) * rs * g[t + 256] + b[t + 256]);
    orow[t + 512] = f2bf((v2 - mu) * rs * g[t + 512] + b[t + 512]);
}

// ---------------- GEMM: C[M,N] = A[M,K](bf16) * W[N,K]^T(bf16) + bias, epilogues ----------------
// EPI: 0 = QKV (bf16 out + transposed-V side write), 1 = proj (+res, fp32 out),
//      2 = FC1 (GELU, bf16 out), 3 = FC2 (+res, fp32 out)
template <int EPI>
__global__ __launch_bounds__(256) void gemm_bt(const unsigned short* __restrict__ A,
                                               const unsigned short* __restrict__ W,
                                               const float* __restrict__ bias,
                                               const float* __restrict__ res,
                                               void* __restrict__ outp,
                                               unsigned short* __restrict__ vt,
                                               int M, int N, int K) {
    __shared__ __align__(16) unsigned short As[128 * 32];
    __shared__ __align__(16) unsigned short Bs[128 * 32];
    const int tid = threadIdx.x;
    const int w = tid >> 6, l = tid & 63;
    const int lr = l >> 4, lc = l & 15;
    const int nb = N >> 7;
    const int bx = blockIdx.x % nb, by = blockIdx.x / nb;
    const int row0 = by << 7, col0 = bx << 7;
    const int wr = w >> 1, wc = w & 1;
    const int srow = tid >> 2, skoff = (tid & 3) * 8;

    f32x4 acc[4][4] = {};

    const unsigned short* Ag0 = A + (size_t)(row0 + srow) * K + skoff;
    const unsigned short* Ag1 = A + (size_t)(row0 + 64 + srow) * K + skoff;
    const unsigned short* Wg0 = W + (size_t)(col0 + srow) * K + skoff;
    const unsigned short* Wg1 = W + (size_t)(col0 + 64 + srow) * K + skoff;
    unsigned short* la0 = &As[(size_t)tid * 8];
    unsigned short* la1 = la0 + 2048;
    unsigned short* lb0 = &Bs[(size_t)tid * 8];
    unsigned short* lb1 = lb0 + 2048;

    for (int k0 = 0; k0 < K; k0 += 32) {
        __syncthreads();
        load16(Ag0 + k0, la0);
        load16(Ag1 + k0, la1);
        load16(Wg0 + k0, lb0);
        load16(Wg1 + k0, lb1);
        __syncthreads();
        short8 af[4], bfr[4];
#pragma unroll
        for (int i = 0; i < 4; i++) af[i] = *(const short8*)&As[(wr * 64 + i * 16 + lc) * 32 + 8 * lr];
#pragma unroll
        for (int j = 0; j < 4; j++) bfr[j] = *(const short8*)&Bs[(wc * 64 + j * 16 + lc) * 32 + 8 * lr];
#pragma unroll
        for (int i = 0; i < 4; i++)
#pragma unroll
            for (int j = 0; j < 4; j++)
                acc[i][j] = __builtin_amdgcn_mfma_f32_16x16x32_bf16(af[i], bfr[j], acc[i][j], 0, 0, 0);
    }

#pragma unroll
    for (int i = 0; i < 4; i++) {
        const int r0 = row0 + wr * 64 + i * 16 + 4 * lr;
#pragma unroll
        for (int j = 0; j < 4; j++) {
            const int col = col0 + wc * 64 + j * 16 + lc;
            const float bv = bias[col];
            if (EPI == 0) {
                unsigned short* qo = (unsigned short*)outp;
                float v[4];
#pragma unroll
                for (int r = 0; r < 4; r++) {
                    v[r] = acc[i][j][r] + bv;
                    qo[(size_t)(r0 + r) * N + col] = f2bf(v[r]);
                }
                if (col >= 2 * EMBED) {  // V part -> transposed per-head layout [bh][d][n]
                    const int hh = (col - 2 * EMBED) >> 6, d = col & 63;
                    const int bb = r0 >> 11, n0 = r0 & (SEQ - 1);
                    ushort4v pk;
#pragma unroll
                    for (int r = 0; r < 4; r++) pk[r] = f2bf(v[r]);
                    *(ushort4v*)&vt[((size_t)(bb * HEADS + hh) * HDIM + d) * SEQ + n0] = pk;
                }
            } else if (EPI == 1 || EPI == 3) {
                float* fo = (float*)outp;
#pragma unroll
                for (int r = 0; r < 4; r++)
                    fo[(size_t)(r0 + r) * N + col] =
                        acc[i][j][r] + bv + res[(size_t)(r0 + r) * N + col];
            } else {
                unsigned short* qo = (unsigned short*)outp;
#pragma unroll
                for (int r = 0; r < 4; r++) {
                    float v = acc[i][j][r] + bv;
                    v = 0.5f * v * (1.0f + erff(v * 0.70710678118f));
                    qo[(size_t)(r0 + r) * N + col] = f2bf(v);
                }
            }
        }
    }
}

// ---------------- Flash attention ----------------
// grid (SEQ/128, BSZ*HEADS), 256 thr. Q tile 128 rows (32/wave), KV tiles 128.
__global__ __launch_bounds__(256) void attn_k(const unsigned short* __restrict__ qkv,
                                              const unsigned short* __restrict__ vt,
                                              unsigned short* __restrict__ o_out) {
    __shared__ __align__(16) unsigned short Ks[128 * 64];    // [kv][d]  XOR-swizzled
    __shared__ __align__(16) unsigned short Vs[64 * 128];    // [d][kv]  XOR-swizzled
    __shared__ __align__(16) unsigned short Ps[4][32 * 136]; // per-wave P, padded

    const int tid = threadIdx.x;
    const int w = tid >> 6, l = tid & 63;
    const int lr = l >> 4, lc = l & 15;
    const int q0 = blockIdx.x * 128;
    const int bh = blockIdx.y;
    const int b = bh / HEADS, h = bh % HEADS;

    // Q fragments (A-operand), scale folded into softmax exp
    short8 aq[2][2];
#pragma unroll
    for (int mi = 0; mi < 2; mi++)
#pragma unroll
        for (int kk = 0; kk < 2; kk++) {
            const int tok = b * SEQ + q0 + w * 32 + mi * 16 + lc;
            aq[mi][kk] = *(const short8*)&qkv[(size_t)tok * QKVN + h * HDIM + kk * 32 + 8 * lr];
        }

    f32x4 oacc[2][4] = {};
    float mst[2][4], lst[2][4];
#pragma unroll
    for (int mi = 0; mi < 2; mi++)
#pragma unroll
        for (int r = 0; r < 4; r++) { mst[mi][r] = -1e30f; lst[mi][r] = 0.0f; }

    for (int kv0 = 0; kv0 < SEQ; kv0 += 128) {
        __syncthreads();
        // stage K tile [128][64], source pre-swizzled so reads can XOR-deswizzle
#pragma unroll
        for (int c = 0; c < 4; c++) {
            const int o = c * 4096 + tid * 16;
            const int krow = o >> 7, pc = o & 127;
            const int lcb = pc ^ ((krow & 7) << 4);
            load16(&qkv[(size_t)(b * SEQ + kv0 + krow) * QKVN + EMBED + h * HDIM + (lcb >> 1)],
                   (char*)Ks + o);
        }
        // stage V^T tile [64][128]
#pragma unroll
        for (int c = 0; c < 4; c++) {
            const int o = c * 4096 + tid * 16;
            const int drow = o >> 8, pc = o & 255;
            const int lcb = pc ^ ((drow & 7) << 4);
            load16(&vt[(size_t)(bh * HDIM + drow) * SEQ + kv0 + (lcb >> 1)], (char*)Vs + o);
        }
        __syncthreads();

        // S = Q K^T
        f32x4 s[2][8] = {};
#pragma unroll
        for (int kk = 0; kk < 2; kk++) {
            short8 bk[8];
#pragma unroll
            for (int nj = 0; nj < 8; nj++) {
                const int krow = nj * 16 + lc;
                const int kb = kk * 64 + lr * 16;
                bk[nj] = *(const short8*)((const char*)Ks + krow * 128 + (kb ^ ((krow & 7) << 4)));
            }
#pragma unroll
            for (int mi = 0; mi < 2; mi++)
#pragma unroll
                for (int nj = 0; nj < 8; nj++)
                    s[mi][nj] = __builtin_amdgcn_mfma_f32_16x16x32_bf16(aq[mi][kk], bk[nj], s[mi][nj], 0, 0, 0);
        }

        // online softmax (scale 0.125 folded into exp args)
        float corr[2][4];
#pragma unroll
        for (int mi = 0; mi < 2; mi++)
#pragma unroll
            for (int r = 0; r < 4; r++) {
                float mt = s[mi][0][r];
#pragma unroll
                for (int nj = 1; nj < 8; nj++) mt = fmaxf(mt, s[mi][nj][r]);
#pragma unroll
                for (int m = 1; m < 16; m <<= 1) mt = fmaxf(mt, __shfl_xor(mt, m));
                const float mn = fmaxf(mst[mi][r], mt);
                const float c_ = __expf((mst[mi][r] - mn) * 0.125f);
                mst[mi][r] = mn;
                corr[mi][r] = c_;
                float rsum = 0.0f;
#pragma unroll
                for (int nj = 0; nj < 8; nj++) {
                    const float pv = __expf((s[mi][nj][r] - mn) * 0.125f);
                    s[mi][nj][r] = pv;
                    rsum += pv;
                }
#pragma unroll
                for (int m = 1; m < 16; m <<= 1) rsum += __shfl_xor(rsum, m);
                lst[mi][r] = lst[mi][r] * c_ + rsum;
#pragma unroll
                for (int dj = 0; dj < 4; dj++) oacc[mi][dj][r] *= c_;
            }

        // P -> per-wave LDS (row-major [q][kv])
#pragma unroll
        for (int mi = 0; mi < 2; mi++)
#pragma unroll
            for (int nj = 0; nj < 8; nj++)
#pragma unroll
                for (int r = 0; r < 4; r++)
                    Ps[w][(mi * 16 + 4 * lr + r) * 136 + nj * 16 + lc] = f2bf(s[mi][nj][r]);

        // O += P V
#pragma unroll
        for (int kk = 0; kk < 4; kk++) {
            short8 pa[2], bv[4];
#pragma unroll
            for (int mi = 0; mi < 2; mi++)
                pa[mi] = *(const short8*)&Ps[w][(mi * 16 + lc) * 136 + kk * 32 + 8 * lr];
#pragma unroll
            for (int dj = 0; dj < 4; dj++) {
                const int drow = dj * 16 + lc;
                const int kb = kk * 64 + lr * 16;
                bv[dj] = *(const short8*)((const char*)Vs + drow * 256 + (kb ^ ((drow & 7) << 4)));
            }
#pragma unroll
            for (int mi = 0; mi < 2; mi++)
#pragma unroll
                for (int dj = 0; dj < 4; dj++)
                    oacc[mi][dj] = __builtin_amdgcn_mfma_f32_16x16x32_bf16(pa[mi], bv[dj], oacc[mi][dj], 0, 0, 0);
        }
    }

#pragma unroll
    for (int mi = 0; mi < 2; mi++)
#pragma unroll
        for (int dj = 0; dj < 4; dj++)
#pragma unroll
            for (int r = 0; r < 4; r++) {
                const int q = q0 + w * 32 + mi * 16 + 4 * lr + r;
                const int col = h * HDIM + dj * 16 + lc;
                o_out[(size_t)(b * SEQ + q) * EMBED + col] = f2bf(oacc[mi][dj][r] / lst[mi][r]);
            }
}

extern "C" void kernel_launch(void* const* d_in, const int* in_sizes, int n_in,
                              void* d_out, int out_size, void* d_ws, size_t ws_size,
                              hipStream_t stream) {
    const float* x      = (const float*)d_in[0];
    const float* ln1_g  = (const float*)d_in[1];
    const float* ln1_b  = (const float*)d_in[2];
    const float* qkv_w  = (const float*)d_in[3];
    const float* qkv_b  = (const float*)d_in[4];
    const float* proj_w = (const float*)d_in[5];
    const float* proj_b = (const float*)d_in[6];
    const float* ln2_g  = (const float*)d_in[7];
    const float* ln2_b  = (const float*)d_in[8];
    const float* fc1_w  = (const float*)d_in[9];
    const float* fc1_b  = (const float*)d_in[10];
    const float* fc2_w  = (const float*)d_in[11];
    const float* fc2_b  = (const float*)d_in[12];

    char* ws = (char*)d_ws;
    unsigned short* hbuf = (unsigned short*)(ws + 0);         // 6.29 MB: h -> o -> h2
    unsigned short* qkv  = (unsigned short*)(ws + 6291456);   // 18.87 MB
    unsigned short* vt   = (unsigned short*)(ws + 25165824);  // 6.29 MB
    float*          x2   = (float*)(ws + 31457280);           // 12.58 MB
    unsigned short* gbuf = (unsigned short*)(ws + 6291456);   // aliases qkv+vt (both dead)
    unsigned short* wq   = (unsigned short*)(ws + 44040192);  // 3.54 MB
    unsigned short* wp   = (unsigned short*)(ws + 47579136);  // 1.18 MB
    unsigned short* w1   = (unsigned short*)(ws + 48758784);  // 4.72 MB
    unsigned short* w2   = (unsigned short*)(ws + 53477376);  // 4.72 MB

    {
        int n4;
        n4 = QKVN * EMBED / 4;
        cvt_k<<<dim3((n4 + 255) / 256 > 2048 ? 2048 : (n4 + 255) / 256), 256, 0, stream>>>(qkv_w, wq, n4);
        n4 = EMBED * EMBED / 4;
        cvt_k<<<dim3((n4 + 255) / 256 > 2048 ? 2048 : (n4 + 255) / 256), 256, 0, stream>>>(proj_w, wp, n4);
        n4 = HIDDEN * EMBED / 4;
        cvt_k<<<dim3((n4 + 255) / 256 > 2048 ? 2048 : (n4 + 255) / 256), 256, 0, stream>>>(fc1_w, w1, n4);
        n4 = EMBED * HIDDEN / 4;
        cvt_k<<<dim3((n4 + 255) / 256 > 2048 ? 2048 : (n4 + 255) / 256), 256, 0, stream>>>(fc2_w, w2, n4);
    }

    ln_k<<<dim3(NTOK), 256, 0, stream>>>(x, ln1_g, ln1_b, hbuf);

    gemm_bt<0><<<dim3((NTOK / 128) * (QKVN / 128)), 256, 0, stream>>>(
        hbuf, wq, qkv_b, nullptr, qkv, vt, NTOK, QKVN, EMBED);

    attn_k<<<dim3(SEQ / 128, BSZ * HEADS), 256, 0, stream>>>(qkv, vt, hbuf);

    gemm_bt<1><<<dim3((NTOK / 128) * (EMBED / 128)), 256, 0, stream>>>(
        hbuf, wp, proj_b, x, x2, nullptr, NTOK, EMBED, EMBED);

    ln_k<<<dim3(NTOK), 256, 0, stream>>>(x2, ln2_g, ln2_b, hbuf);

    gemm_bt<2><<<dim3((NTOK / 128) * (HIDDEN / 128)), 256, 0, stream>>>(
        hbuf, w1, fc1_b, nullptr, gbuf, nullptr, NTOK, HIDDEN, EMBED);

    gemm_bt<3><<<dim3((NTOK / 128) * (EMBED / 128)), 256, 0, stream>>>(
        gbuf, w2, fc2_b, x2, d_out, nullptr, NTOK, EMBED, HIDDEN);
}

// Round 2
// 355.978 us; speedup vs baseline: 1.2206x; 1.2206x over previous
//
#include <hip/hip_runtime.h>
#include <stdint.h>

#define EMBED  768
#define HEADS  12
#define HDIM   64
#define HIDDEN 3072
#define BSZ    2
#define SEQ    2048
#define NTOK   4096
#define QKVN   2304

typedef short short8 __attribute__((ext_vector_type(8)));
typedef float f32x4 __attribute__((ext_vector_type(4)));
typedef float float4v __attribute__((ext_vector_type(4)));
typedef unsigned short ushort4v __attribute__((ext_vector_type(4)));

__device__ __forceinline__ unsigned short f2bf(float f) {
    uint32_t x = __builtin_bit_cast(uint32_t, f);
    x = x + 0x7fffu + ((x >> 16) & 1u);   // RNE
    return (unsigned short)(x >> 16);
}
__device__ __forceinline__ float bf2f(unsigned short u) {
    uint32_t x = ((uint32_t)u) << 16;
    return __builtin_bit_cast(float, x);
}
__device__ __forceinline__ void load16(const void* g, void* l) {
    __builtin_amdgcn_global_load_lds((const __attribute__((address_space(1))) void*)g,
                                     (__attribute__((address_space(3))) void*)l, 16, 0, 0);
}

// ---------------- fp32 -> bf16 convert ----------------
__global__ __launch_bounds__(256) void cvt_k(const float* __restrict__ in,
                                             unsigned short* __restrict__ out, int n4) {
    int i = blockIdx.x * blockDim.x + threadIdx.x;
    int stride = gridDim.x * blockDim.x;
    for (; i < n4; i += stride) {
        float4v v = ((const float4v*)in)[i];
        ushort4v o;
#pragma unroll
        for (int j = 0; j < 4; j++) o[j] = f2bf(v[j]);
        ((ushort4v*)out)[i] = o;
    }
}

// ---------------- LayerNorm (fp32 in, bf16 out) ----------------
__global__ __launch_bounds__(256) void ln_k(const float* __restrict__ x,
                                            const float* __restrict__ g,
                                            const float* __restrict__ b,
                                            unsigned short* __restrict__ out) {
    const int row = blockIdx.x;
    const int t = threadIdx.x;
    const float* xr = x + (size_t)row * EMBED;
    float v0 = xr[t], v1 = xr[t + 256], v2 = xr[t + 512];
    float s = v0 + v1 + v2;
    float s2 = v0 * v0 + v1 * v1 + v2 * v2;
#pragma unroll
    for (int m = 1; m < 64; m <<= 1) { s += __shfl_xor(s, m); s2 += __shfl_xor(s2, m); }
    __shared__ float red[8];
    const int w = t >> 6;
    if ((t & 63) == 0) { red[w] = s; red[4 + w] = s2; }
    __syncthreads();
    s = red[0] + red[1] + red[2] + red[3];
    s2 = red[4] + red[5] + red[6] + red[7];
    const float mu = s * (1.0f / EMBED);
    const float var = s2 * (1.0f / EMBED) - mu * mu;
    const float rs = rsqrtf(var + 1e-5f);
    unsigned short* orow = out + (size_t)row * EMBED;
    orow[t]       = f2bf((v0 - mu) * rs * g[t]       + b[t]);
    orow[t + 256] = f2bf((v1 - mu) * rs * g[t + 256] + b[t + 256]);
    orow[t + 512] = f2bf((v2 - mu) * rs * g[t + 512] + b[t + 512]);
}

// ---------------- GEMM: C[M,N] = A[M,K](bf16) * W[N,K]^T(bf16) + bias, epilogues ----------------
// EPI: 0 = QKV (bf16 out + transposed-V side write), 1 = proj (+res, fp32 out),
//      2 = FC1 (GELU, bf16 out), 3 = FC2 (+res, fp32 out)
template <int EPI>
__global__ __launch_bounds__(256) void gemm_bt(const unsigned short* __restrict__ A,
                                               const unsigned short* __restrict__ W,
                                               const float* __restrict__ bias,
                                               const float* __restrict__ res,
                                               void* __restrict__ outp,
                                               unsigned short* __restrict__ vt,
                                               int M, int N, int K) {
    __shared__ __align__(16) unsigned short As[128 * 32];
    __shared__ __align__(16) unsigned short Bs[128 * 32];
    const int tid = threadIdx.x;
    const int w = tid >> 6, l = tid & 63;
    const int lr = l >> 4, lc = l & 15;
    const int nb = N >> 7;
    const int bx = blockIdx.x % nb, by = blockIdx.x / nb;
    const int row0 = by << 7, col0 = bx << 7;
    const int wr = w >> 1, wc = w & 1;
    const int srow = tid >> 2, skoff = (tid & 3) * 8;

    f32x4 acc[4][4] = {};

    const unsigned short* Ag0 = A + (size_t)(row0 + srow) * K + skoff;
    const unsigned short* Ag1 = A + (size_t)(row0 + 64 + srow) * K + skoff;
    const unsigned short* Wg0 = W + (size_t)(col0 + srow) * K + skoff;
    const unsigned short* Wg1 = W + (size_t)(col0 + 64 + srow) * K + skoff;
    unsigned short* la0 = &As[(size_t)tid * 8];
    unsigned short* la1 = la0 + 2048;
    unsigned short* lb0 = &Bs[(size_t)tid * 8];
    unsigned short* lb1 = lb0 + 2048;

    for (int k0 = 0; k0 < K; k0 += 32) {
        __syncthreads();
        load16(Ag0 + k0, la0);
        load16(Ag1 + k0, la1);
        load16(Wg0 + k0, lb0);
        load16(Wg1 + k0, lb1);
        __syncthreads();
        short8 af[4], bfr[4];
#pragma unroll
        for (int i = 0; i < 4; i++) af[i] = *(const short8*)&As[(wr * 64 + i * 16 + lc) * 32 + 8 * lr];
#pragma unroll
        for (int j = 0; j < 4; j++) bfr[j] = *(const short8*)&Bs[(wc * 64 + j * 16 + lc) * 32 + 8 * lr];
#pragma unroll
        for (int i = 0; i < 4; i++)
#pragma unroll
            for (int j = 0; j < 4; j++)
                acc[i][j] = __builtin_amdgcn_mfma_f32_16x16x32_bf16(af[i], bfr[j], acc[i][j], 0, 0, 0);
    }

#pragma unroll
    for (int i = 0; i < 4; i++) {
        const int r0 = row0 + wr * 64 + i * 16 + 4 * lr;
#pragma unroll
        for (int j = 0; j < 4; j++) {
            const int col = col0 + wc * 64 + j * 16 + lc;
            const float bv = bias[col];
            if (EPI == 0) {
                unsigned short* qo = (unsigned short*)outp;
                float v[4];
#pragma unroll
                for (int r = 0; r < 4; r++) {
                    v[r] = acc[i][j][r] + bv;
                    qo[(size_t)(r0 + r) * N + col] = f2bf(v[r]);
                }
                if (col >= 2 * EMBED) {  // V part -> transposed per-head layout [bh][d][n]
                    const int hh = (col - 2 * EMBED) >> 6, d = col & 63;
                    const int bb = r0 >> 11, n0 = r0 & (SEQ - 1);
                    ushort4v pk;
#pragma unroll
                    for (int r = 0; r < 4; r++) pk[r] = f2bf(v[r]);
                    *(ushort4v*)&vt[((size_t)(bb * HEADS + hh) * HDIM + d) * SEQ + n0] = pk;
                }
            } else if (EPI == 1 || EPI == 3) {
                float* fo = (float*)outp;
#pragma unroll
                for (int r = 0; r < 4; r++)
                    fo[(size_t)(r0 + r) * N + col] =
                        acc[i][j][r] + bv + res[(size_t)(r0 + r) * N + col];
            } else {
                unsigned short* qo = (unsigned short*)outp;
#pragma unroll
                for (int r = 0; r < 4; r++) {
                    float v = acc[i][j][r] + bv;
                    v = 0.5f * v * (1.0f + erff(v * 0.70710678118f));
                    qo[(size_t)(r0 + r) * N + col] = f2bf(v);
                }
            }
        }
    }
}

// ---------------- Flash attention ----------------
// grid (SEQ/64, BSZ*HEADS), 256 thr. Q tile 64 rows (16/wave), KV tiles 128.
// 768 blocks -> 3 blocks/CU co-resident (LDS 50KB); barrier drains in one block
// overlap with compute in the other two.
__global__ __launch_bounds__(256) void attn_k(const unsigned short* __restrict__ qkv,
                                              const unsigned short* __restrict__ vt,
                                              unsigned short* __restrict__ o_out) {
    __shared__ __align__(16) unsigned short Ks[128 * 64];    // [kv][d]  XOR-swizzled
    __shared__ __align__(16) unsigned short Vs[64 * 128];    // [d][kv]  XOR-swizzled
    __shared__ __align__(16) unsigned short Ps[4][16 * 136]; // per-wave P, padded

    const int tid = threadIdx.x;
    const int w = tid >> 6, l = tid & 63;
    const int lr = l >> 4, lc = l & 15;
    const int q0 = blockIdx.x * 64;
    const int bh = blockIdx.y;
    const int b = bh / HEADS, h = bh % HEADS;

    // Q fragments (A-operand), scale folded into softmax exp
    short8 aq[2];
#pragma unroll
    for (int kk = 0; kk < 2; kk++) {
        const int tok = b * SEQ + q0 + w * 16 + lc;
        aq[kk] = *(const short8*)&qkv[(size_t)tok * QKVN + h * HDIM + kk * 32 + 8 * lr];
    }

    f32x4 oacc[4] = {};
    float mst[4], lst[4];
#pragma unroll
    for (int r = 0; r < 4; r++) { mst[r] = -1e30f; lst[r] = 0.0f; }

    for (int kv0 = 0; kv0 < SEQ; kv0 += 128) {
        __syncthreads();
        // stage K tile [128][64], source pre-swizzled so reads can XOR-deswizzle
#pragma unroll
        for (int c = 0; c < 4; c++) {
            const int o = c * 4096 + tid * 16;
            const int krow = o >> 7, pc = o & 127;
            const int lcb = pc ^ ((krow & 7) << 4);
            load16(&qkv[(size_t)(b * SEQ + kv0 + krow) * QKVN + EMBED + h * HDIM + (lcb >> 1)],
                   (char*)Ks + o);
        }
        // stage V^T tile [64][128]
#pragma unroll
        for (int c = 0; c < 4; c++) {
            const int o = c * 4096 + tid * 16;
            const int drow = o >> 8, pc = o & 255;
            const int lcb = pc ^ ((drow & 7) << 4);
            load16(&vt[(size_t)(bh * HDIM + drow) * SEQ + kv0 + (lcb >> 1)], (char*)Vs + o);
        }
        __syncthreads();

        // S = Q K^T   (16 q-rows x 128 kv)
        f32x4 s[8] = {};
#pragma unroll
        for (int kk = 0; kk < 2; kk++) {
            short8 bk[8];
#pragma unroll
            for (int nj = 0; nj < 8; nj++) {
                const int krow = nj * 16 + lc;
                const int kb = kk * 64 + lr * 16;
                bk[nj] = *(const short8*)((const char*)Ks + krow * 128 + (kb ^ ((krow & 7) << 4)));
            }
#pragma unroll
            for (int nj = 0; nj < 8; nj++)
                s[nj] = __builtin_amdgcn_mfma_f32_16x16x32_bf16(aq[kk], bk[nj], s[nj], 0, 0, 0);
        }

        // online softmax (scale 0.125 folded into exp args)
#pragma unroll
        for (int r = 0; r < 4; r++) {
            float mt = s[0][r];
#pragma unroll
            for (int nj = 1; nj < 8; nj++) mt = fmaxf(mt, s[nj][r]);
#pragma unroll
            for (int m = 1; m < 16; m <<= 1) mt = fmaxf(mt, __shfl_xor(mt, m));
            const float mn = fmaxf(mst[r], mt);
            const float c_ = __expf((mst[r] - mn) * 0.125f);
            mst[r] = mn;
            float rsum = 0.0f;
#pragma unroll
            for (int nj = 0; nj < 8; nj++) {
                const float pv = __expf((s[nj][r] - mn) * 0.125f);
                s[nj][r] = pv;
                rsum += pv;
            }
#pragma unroll
            for (int m = 1; m < 16; m <<= 1) rsum += __shfl_xor(rsum, m);
            lst[r] = lst[r] * c_ + rsum;
#pragma unroll
            for (int dj = 0; dj < 4; dj++) oacc[dj][r] *= c_;
        }

        // P -> per-wave LDS (row-major [q][kv])
#pragma unroll
        for (int nj = 0; nj < 8; nj++)
#pragma unroll
            for (int r = 0; r < 4; r++)
                Ps[w][(4 * lr + r) * 136 + nj * 16 + lc] = f2bf(s[nj][r]);

        // O += P V
#pragma unroll
        for (int kk = 0; kk < 4; kk++) {
            short8 pa, bv[4];
            pa = *(const short8*)&Ps[w][lc * 136 + kk * 32 + 8 * lr];
#pragma unroll
            for (int dj = 0; dj < 4; dj++) {
                const int drow = dj * 16 + lc;
                const int kb = kk * 64 + lr * 16;
                bv[dj] = *(const short8*)((const char*)Vs + drow * 256 + (kb ^ ((drow & 7) << 4)));
            }
#pragma unroll
            for (int dj = 0; dj < 4; dj++)
                oacc[dj] = __builtin_amdgcn_mfma_f32_16x16x32_bf16(pa, bv[dj], oacc[dj], 0, 0, 0);
        }
    }

#pragma unroll
    for (int dj = 0; dj < 4; dj++)
#pragma unroll
        for (int r = 0; r < 4; r++) {
            const int q = q0 + w * 16 + 4 * lr + r;
            const int col = h * HDIM + dj * 16 + lc;
            o_out[(size_t)(b * SEQ + q) * EMBED + col] = f2bf(oacc[dj][r] / lst[r]);
        }
}

extern "C" void kernel_launch(void* const* d_in, const int* in_sizes, int n_in,
                              void* d_out, int out_size, void* d_ws, size_t ws_size,
                              hipStream_t stream) {
    const float* x      = (const float*)d_in[0];
    const float* ln1_g  = (const float*)d_in[1];
    const float* ln1_b  = (const float*)d_in[2];
    const float* qkv_w  = (const float*)d_in[3];
    const float* qkv_b  = (const float*)d_in[4];
    const float* proj_w = (const float*)d_in[5];
    const float* proj_b = (const float*)d_in[6];
    const float* ln2_g  = (const float*)d_in[7];
    const float* ln2_b  = (const float*)d_in[8];
    const float* fc1_w  = (const float*)d_in[9];
    const float* fc1_b  = (const float*)d_in[10];
    const float* fc2_w  = (const float*)d_in[11];
    const float* fc2_b  = (const float*)d_in[12];

    char* ws = (char*)d_ws;
    unsigned short* hbuf = (unsigned short*)(ws + 0);         // 6.29 MB: h -> o -> h2
    unsigned short* qkv  = (unsigned short*)(ws + 6291456);   // 18.87 MB
    unsigned short* vt   = (unsigned short*)(ws + 25165824);  // 6.29 MB
    float*          x2   = (float*)(ws + 31457280);           // 12.58 MB
    unsigned short* gbuf = (unsigned short*)(ws + 6291456);   // aliases qkv+vt (both dead)
    unsigned short* wq   = (unsigned short*)(ws + 44040192);  // 3.54 MB
    unsigned short* wp   = (unsigned short*)(ws + 47579136);  // 1.18 MB
    unsigned short* w1   = (unsigned short*)(ws + 48758784);  // 4.72 MB
    unsigned short* w2   = (unsigned short*)(ws + 53477376);  // 4.72 MB

    {
        int n4;
        n4 = QKVN * EMBED / 4;
        cvt_k<<<dim3((n4 + 255) / 256 > 2048 ? 2048 : (n4 + 255) / 256), 256, 0, stream>>>(qkv_w, wq, n4);
        n4 = EMBED * EMBED / 4;
        cvt_k<<<dim3((n4 + 255) / 256 > 2048 ? 2048 : (n4 + 255) / 256), 256, 0, stream>>>(proj_w, wp, n4);
        n4 = HIDDEN * EMBED / 4;
        cvt_k<<<dim3((n4 + 255) / 256 > 2048 ? 2048 : (n4 + 255) / 256), 256, 0, stream>>>(fc1_w, w1, n4);
        n4 = EMBED * HIDDEN / 4;
        cvt_k<<<dim3((n4 + 255) / 256 > 2048 ? 2048 : (n4 + 255) / 256), 256, 0, stream>>>(fc2_w, w2, n4);
    }

    ln_k<<<dim3(NTOK), 256, 0, stream>>>(x, ln1_g, ln1_b, hbuf);

    gemm_bt<0><<<dim3((NTOK / 128) * (QKVN / 128)), 256, 0, stream>>>(
        hbuf, wq, qkv_b, nullptr, qkv, vt, NTOK, QKVN, EMBED);

    attn_k<<<dim3(SEQ / 64, BSZ * HEADS), 256, 0, stream>>>(qkv, vt, hbuf);

    gemm_bt<1><<<dim3((NTOK / 128) * (EMBED / 128)), 256, 0, stream>>>(
        hbuf, wp, proj_b, x, x2, nullptr, NTOK, EMBED, EMBED);

    ln_k<<<dim3(NTOK), 256, 0, stream>>>(x2, ln2_g, ln2_b, hbuf);

    gemm_bt<2><<<dim3((NTOK / 128) * (HIDDEN / 128)), 256, 0, stream>>>(
        hbuf, w1, fc1_b, nullptr, gbuf, nullptr, NTOK, HIDDEN, EMBED);

    gemm_bt<3><<<dim3((NTOK / 128) * (EMBED / 128)), 256, 0, stream>>>(
        gbuf, w2, fc2_b, x2, d_out, nullptr, NTOK, EMBED, HIDDEN);
}